// Round 1
// baseline (2511.283 us; speedup 1.0000x reference)
//
#include <hip/hip_runtime.h>

#define N_NODES 100000
#define N_EDGES 1600000
#define IN_H 18
#define OUT_H 11
#define NCLASS 40
#define NHID 256

// ---------------- degree / dinv ----------------
__global__ void k_deg_init(float* deg, int n) {
    int i = blockIdx.x * blockDim.x + threadIdx.x;
    if (i < n) deg[i] = 1.0f;   // self-loop
}

__global__ void k_deg_count(const int* __restrict__ dst, float* deg, int E) {
    int e = blockIdx.x * blockDim.x + threadIdx.x;
    if (e < E) atomicAdd(&deg[dst[e]], 1.0f);
}

__global__ void k_dinv(float* deg, int n) {
    int i = blockIdx.x * blockDim.x + threadIdx.x;
    if (i < n) deg[i] = rsqrtf(deg[i]);   // deg >= 1 always
}

// ---------------- W12 = W1 @ W2, bb = b1 @ W2 (one block) ----------------
__global__ void k_w12(const float* __restrict__ W1, const float* __restrict__ b1,
                      const float* __restrict__ W2,
                      float* __restrict__ W12, float* __restrict__ bb) {
    int t = threadIdx.x;
    if (t < IN_H * OUT_H) {
        int i = t / OUT_H, j = t % OUT_H;
        float s = 0.f;
        for (int k = 0; k < NHID; ++k) s += W1[i * NHID + k] * W2[k * OUT_H + j];
        W12[t] = s;
    } else if (t < IN_H * OUT_H + OUT_H) {
        int j = t - IN_H * OUT_H;
        float s = 0.f;
        for (int k = 0; k < NHID; ++k) s += b1[k] * W2[k * OUT_H + j];
        bb[j] = s;
    }
}

// ---------------- Z = dinv^2 * X (self-loop term), elementwise ----------------
__global__ void k_z_init(const float* __restrict__ X, const float* __restrict__ dinv,
                         float* __restrict__ Z, int n_elem) {
    int idx = blockIdx.x * blockDim.x + threadIdx.x;
    if (idx < n_elem) {
        int v = idx / IN_H;
        float d = dinv[v];
        Z[idx] = d * d * X[idx];
    }
}

// ---------------- edge scatter, 18 features: Z[dst] += X[src]*norm ----------------
__global__ void k_scatter18(const int* __restrict__ ei, const float* __restrict__ X,
                            const float* __restrict__ dinv, float* __restrict__ Z, int E) {
    int e = blockIdx.x * blockDim.x + threadIdx.x;
    if (e >= E) return;
    int s = ei[e];
    int d = ei[E + e];
    float norm = dinv[s] * dinv[d];
    const float2* xs = (const float2*)(X + (size_t)s * IN_H);  // 72B row, 8B aligned
    float* zd = Z + (size_t)d * IN_H;
    #pragma unroll
    for (int k = 0; k < IN_H / 2; ++k) {
        float2 c = xs[k];
        atomicAdd(&zd[2 * k],     c.x * norm);
        atomicAdd(&zd[2 * k + 1], c.y * norm);
    }
}

// ---------------- M = Z @ W12 + bb ; H2 = dinv^2 * M (self-loop init) ----------------
__global__ void k_m_h2init(const float* __restrict__ Z, const float* __restrict__ W12g,
                           const float* __restrict__ bbg, const float* __restrict__ dinv,
                           float* __restrict__ M, float* __restrict__ H2, int n) {
    __shared__ float sW[IN_H * OUT_H];
    __shared__ float sb[OUT_H];
    int t = threadIdx.x;
    if (t < IN_H * OUT_H) sW[t] = W12g[t];
    if (t < OUT_H) sb[t] = bbg[t];
    __syncthreads();
    int v = blockIdx.x * blockDim.x + t;
    if (v >= n) return;
    float x[IN_H];
    const float2* zr = (const float2*)(Z + (size_t)v * IN_H);
    #pragma unroll
    for (int k = 0; k < IN_H / 2; ++k) {
        float2 c = zr[k];
        x[2 * k] = c.x; x[2 * k + 1] = c.y;
    }
    float dv = dinv[v];
    float d2 = dv * dv;
    #pragma unroll
    for (int j = 0; j < OUT_H; ++j) {
        float s = sb[j];
        #pragma unroll
        for (int k = 0; k < IN_H; ++k) s += x[k] * sW[k * OUT_H + j];
        M[(size_t)v * OUT_H + j]  = s;
        H2[(size_t)v * OUT_H + j] = d2 * s;
    }
}

// ---------------- edge scatter, 11 features: H2[dst] += M[src]*norm ----------------
__global__ void k_scatter11(const int* __restrict__ ei, const float* __restrict__ M,
                            const float* __restrict__ dinv, float* __restrict__ H2, int E) {
    int e = blockIdx.x * blockDim.x + threadIdx.x;
    if (e >= E) return;
    int s = ei[e];
    int d = ei[E + e];
    float norm = dinv[s] * dinv[d];
    const float* ms = M + (size_t)s * OUT_H;
    float* hd = H2 + (size_t)d * OUT_H;
    #pragma unroll
    for (int k = 0; k < OUT_H; ++k) atomicAdd(&hd[k], ms[k] * norm);
}

// ---------------- out = emb_a @ Wc[:40] + relu(H2 + b2) @ Wc[40:] + bc ----------------
__global__ void k_final(const float* __restrict__ emb_a, const float* __restrict__ H2,
                        const float* __restrict__ b2g, const float* __restrict__ Wc,
                        const float* __restrict__ bc, float* __restrict__ out, int n) {
    __shared__ float sWc[(NCLASS + OUT_H) * NCLASS];  // 51*40 = 2040 floats
    __shared__ float sbc[NCLASS];
    __shared__ float sb2[OUT_H];
    for (int t = threadIdx.x; t < (NCLASS + OUT_H) * NCLASS; t += blockDim.x) sWc[t] = Wc[t];
    if (threadIdx.x < NCLASS) sbc[threadIdx.x] = bc[threadIdx.x];
    if (threadIdx.x < OUT_H)  sb2[threadIdx.x] = b2g[threadIdx.x];
    __syncthreads();
    int v = blockIdx.x * blockDim.x + threadIdx.x;
    if (v >= n) return;
    float acc[NCLASS];
    #pragma unroll
    for (int j = 0; j < NCLASS; ++j) acc[j] = sbc[j];
    const float2* ea = (const float2*)(emb_a + (size_t)v * NCLASS);  // 160B row
    #pragma unroll
    for (int k2 = 0; k2 < NCLASS / 2; ++k2) {
        float2 a = ea[k2];
        #pragma unroll
        for (int j = 0; j < NCLASS; ++j) {
            acc[j] += a.x * sWc[(2 * k2)     * NCLASS + j];
            acc[j] += a.y * sWc[(2 * k2 + 1) * NCLASS + j];
        }
    }
    #pragma unroll
    for (int k = 0; k < OUT_H; ++k) {
        float h = H2[(size_t)v * OUT_H + k] + sb2[k];
        h = h > 0.f ? h : 0.f;   // relu
        #pragma unroll
        for (int j = 0; j < NCLASS; ++j) acc[j] += h * sWc[(NCLASS + k) * NCLASS + j];
    }
    float* orow = out + (size_t)v * NCLASS;
    #pragma unroll
    for (int j = 0; j < NCLASS; ++j) orow[j] = acc[j];
}

extern "C" void kernel_launch(void* const* d_in, const int* in_sizes, int n_in,
                              void* d_out, int out_size, void* d_ws, size_t ws_size,
                              hipStream_t stream) {
    const float* X     = (const float*)d_in[0];   // [100000, 18]
    const int*   ei    = (const int*)d_in[1];     // [2, 1600000]
    const float* emb_a = (const float*)d_in[2];   // [100000, 40]
    const float* W1    = (const float*)d_in[3];   // [18, 256]
    const float* b1    = (const float*)d_in[4];   // [256]
    const float* W2    = (const float*)d_in[5];   // [256, 11]
    const float* b2    = (const float*)d_in[6];   // [11]
    const float* Wc    = (const float*)d_in[7];   // [51, 40]
    const float* bc    = (const float*)d_in[8];   // [40]
    float* out = (float*)d_out;

    // workspace layout (256B-aligned chunks)
    char* ws = (char*)d_ws;
    size_t off = 0;
    auto alloc = [&](size_t nfloats) {
        float* p = (float*)(ws + off);
        off += ((nfloats * sizeof(float) + 255) / 256) * 256;
        return p;
    };
    float* dinv = alloc(N_NODES);            // deg -> dinv in place
    float* Z    = alloc((size_t)N_NODES * IN_H);
    float* M    = alloc((size_t)N_NODES * OUT_H);
    float* H2   = alloc((size_t)N_NODES * OUT_H);
    float* W12  = alloc(IN_H * OUT_H);
    float* bb   = alloc(OUT_H);

    const int B = 256;
    int gN  = (N_NODES + B - 1) / B;              // 391
    int gE  = (N_EDGES + B - 1) / B;              // 6250
    int gZ  = (N_NODES * IN_H + B - 1) / B;       // 7032

    k_deg_init <<<gN, B, 0, stream>>>(dinv, N_NODES);
    k_deg_count<<<gE, B, 0, stream>>>(ei + N_EDGES, dinv, N_EDGES);
    k_dinv     <<<gN, B, 0, stream>>>(dinv, N_NODES);
    k_w12      <<<1,  B, 0, stream>>>(W1, b1, W2, W12, bb);
    k_z_init   <<<gZ, B, 0, stream>>>(X, dinv, Z, N_NODES * IN_H);
    k_scatter18<<<gE, B, 0, stream>>>(ei, X, dinv, Z, N_EDGES);
    k_m_h2init <<<gN, B, 0, stream>>>(Z, W12, bb, dinv, M, H2, N_NODES);
    k_scatter11<<<gE, B, 0, stream>>>(ei, M, dinv, H2, N_EDGES);
    k_final    <<<gN, B, 0, stream>>>(emb_a, H2, b2, Wc, bc, out, N_NODES);
}

// Round 2
// 310.050 us; speedup vs baseline: 8.0996x; 8.0996x over previous
//
#include <hip/hip_runtime.h>

#define N_NODES 100000
#define N_EDGES 1600000
#define IN_H 18
#define OUT_H 11
#define NCLASS 40
#define NHID 256
#define PSTRIDE 12            // 11 features padded to 12 floats (48B, float4-able)
#define SCAN_B 1024
#define NB_SCAN ((N_NODES + SCAN_B - 1) / SCAN_B)   // 98

// ---------------- init counts ----------------
__global__ void k_cnt_init(int* cnt, int n) {
    int i = blockIdx.x * blockDim.x + threadIdx.x;
    if (i < n) cnt[i] = 0;
}

// ---------------- indegree count (int atomics) ----------------
__global__ void k_count(const int* __restrict__ dst, int* __restrict__ cnt, int E) {
    int e = blockIdx.x * blockDim.x + threadIdx.x;
    if (e < E) atomicAdd(&cnt[dst[e]], 1);
}

// ---------------- scan pass A: per-block inclusive scan ----------------
__global__ void k_scanA(const int* __restrict__ cnt, int* __restrict__ incl,
                        int* __restrict__ bsum, int n) {
    __shared__ int s[SCAN_B];
    int t = threadIdx.x;
    int i = blockIdx.x * SCAN_B + t;
    int v = (i < n) ? cnt[i] : 0;
    s[t] = v;
    __syncthreads();
    for (int off = 1; off < SCAN_B; off <<= 1) {
        int add = (t >= off) ? s[t - off] : 0;
        __syncthreads();
        s[t] += add;
        __syncthreads();
    }
    if (i < n) incl[i] = s[t];
    if (t == SCAN_B - 1) bsum[blockIdx.x] = s[t];
}

// ---------------- scan pass B: exclusive scan of block sums (1 thread) ----------------
__global__ void k_scanB(const int* __restrict__ bsum, int* __restrict__ boff, int nb) {
    if (threadIdx.x == 0 && blockIdx.x == 0) {
        int run = 0;
        for (int b = 0; b < nb; ++b) { boff[b] = run; run += bsum[b]; }
    }
}

// ---------------- scan pass C: rowptr/cursor + dinv ----------------
__global__ void k_scanC(const int* __restrict__ cnt, const int* __restrict__ incl,
                        const int* __restrict__ boff, int* __restrict__ rowptr,
                        int* __restrict__ cursor, float* __restrict__ dinv, int n) {
    int i = blockIdx.x * blockDim.x + threadIdx.x;
    if (i >= n) return;
    int ex = incl[i] - cnt[i] + boff[i >> 10];   // exclusive prefix
    rowptr[i] = ex;
    cursor[i] = ex;
    dinv[i] = rsqrtf((float)(cnt[i] + 1));       // deg = indegree + self-loop
    if (i == 0) rowptr[n] = N_EDGES;
}

// ---------------- fill CSR col array ----------------
__global__ void k_fill(const int* __restrict__ ei, int* __restrict__ cursor,
                       int* __restrict__ col, int E) {
    int e = blockIdx.x * blockDim.x + threadIdx.x;
    if (e >= E) return;
    int s = ei[e];
    int d = ei[E + e];
    int slot = atomicAdd(&cursor[d], 1);
    col[slot] = s;
}

// ---------------- W12 = W1 @ W2, bb = b1 @ W2 (one block) ----------------
__global__ void k_w12(const float* __restrict__ W1, const float* __restrict__ b1,
                      const float* __restrict__ W2,
                      float* __restrict__ W12, float* __restrict__ bb) {
    int t = threadIdx.x;
    if (t < IN_H * OUT_H) {
        int i = t / OUT_H, j = t % OUT_H;
        float s = 0.f;
        for (int k = 0; k < NHID; ++k) s += W1[i * NHID + k] * W2[k * OUT_H + j];
        W12[t] = s;
    } else if (t < IN_H * OUT_H + OUT_H) {
        int j = t - IN_H * OUT_H;
        float s = 0.f;
        for (int k = 0; k < NHID; ++k) s += b1[k] * W2[k * OUT_H + j];
        bb[j] = s;
    }
}

// ---------------- P' = dinv * (X @ W12), padded rows ----------------
__global__ void k_P(const float* __restrict__ X, const float* __restrict__ W12g,
                    const float* __restrict__ dinv, float* __restrict__ Pp, int n) {
    __shared__ float sW[IN_H * OUT_H];
    int t = threadIdx.x;
    if (t < IN_H * OUT_H) sW[t] = W12g[t];
    __syncthreads();
    int v = blockIdx.x * blockDim.x + t;
    if (v >= n) return;
    float x[IN_H];
    const float2* xr = (const float2*)(X + (size_t)v * IN_H);
    #pragma unroll
    for (int k = 0; k < IN_H / 2; ++k) {
        float2 c = xr[k];
        x[2 * k] = c.x; x[2 * k + 1] = c.y;
    }
    float dv = dinv[v];
    float* pr = Pp + (size_t)v * PSTRIDE;
    #pragma unroll
    for (int j = 0; j < OUT_H; ++j) {
        float s = 0.f;
        #pragma unroll
        for (int k = 0; k < IN_H; ++k) s += x[k] * sW[k * OUT_H + j];
        pr[j] = dv * s;
    }
    pr[OUT_H] = 0.f;
}

// ---------------- gather pass 1: Z1' = dinv^2*(sum P'[src] + P'[v]), r ----------------
__global__ void k_gather1(const int* __restrict__ rowptr, const int* __restrict__ col,
                          const float* __restrict__ dinv, const float* __restrict__ Pp,
                          float* __restrict__ Z1p, float* __restrict__ r, int n) {
    int v = blockIdx.x * blockDim.x + threadIdx.x;
    if (v >= n) return;
    int beg = rowptr[v], end = rowptr[v + 1];
    float acc[11];
    #pragma unroll
    for (int j = 0; j < 11; ++j) acc[j] = 0.f;
    float rs = 0.f;
    for (int e = beg; e < end; ++e) {
        int s = col[e];
        rs += dinv[s];
        const float4* p = (const float4*)(Pp + (size_t)s * PSTRIDE);
        float4 a = p[0], b = p[1], c = p[2];
        acc[0] += a.x; acc[1] += a.y; acc[2] += a.z; acc[3] += a.w;
        acc[4] += b.x; acc[5] += b.y; acc[6] += b.z; acc[7] += b.w;
        acc[8] += c.x; acc[9] += c.y; acc[10] += c.z;
    }
    // self-loop term
    {
        const float4* p = (const float4*)(Pp + (size_t)v * PSTRIDE);
        float4 a = p[0], b = p[1], c = p[2];
        acc[0] += a.x; acc[1] += a.y; acc[2] += a.z; acc[3] += a.w;
        acc[4] += b.x; acc[5] += b.y; acc[6] += b.z; acc[7] += b.w;
        acc[8] += c.x; acc[9] += c.y; acc[10] += c.z;
    }
    float dd = dinv[v];
    float s2 = dd * dd;
    float* z = Z1p + (size_t)v * PSTRIDE;
    #pragma unroll
    for (int j = 0; j < 11; ++j) z[j] = s2 * acc[j];
    z[OUT_H] = 0.f;
    r[v] = dd * (rs + dd);
}

// ---------------- gather pass 2 fused with final matmul ----------------
__global__ void k_final(const int* __restrict__ rowptr, const int* __restrict__ col,
                        const float* __restrict__ dinv, const float* __restrict__ Z1p,
                        const float* __restrict__ r, const float* __restrict__ bbg,
                        const float* __restrict__ b2g, const float* __restrict__ emb_a,
                        const float* __restrict__ Wc, const float* __restrict__ bc,
                        float* __restrict__ out, int n) {
    __shared__ float sWc[(NCLASS + OUT_H) * NCLASS];   // 51*40
    __shared__ float sbc[NCLASS];
    __shared__ float sb2[OUT_H];
    __shared__ float sbb[OUT_H];
    for (int t = threadIdx.x; t < (NCLASS + OUT_H) * NCLASS; t += blockDim.x) sWc[t] = Wc[t];
    if (threadIdx.x < NCLASS) sbc[threadIdx.x] = bc[threadIdx.x];
    if (threadIdx.x < OUT_H) { sb2[threadIdx.x] = b2g[threadIdx.x]; sbb[threadIdx.x] = bbg[threadIdx.x]; }
    __syncthreads();
    int v = blockIdx.x * blockDim.x + threadIdx.x;
    if (v >= n) return;
    int beg = rowptr[v], end = rowptr[v + 1];
    float acc[11];
    #pragma unroll
    for (int j = 0; j < 11; ++j) acc[j] = 0.f;
    for (int e = beg; e < end; ++e) {
        int s = col[e];
        const float4* p = (const float4*)(Z1p + (size_t)s * PSTRIDE);
        float4 a = p[0], b = p[1], c = p[2];
        acc[0] += a.x; acc[1] += a.y; acc[2] += a.z; acc[3] += a.w;
        acc[4] += b.x; acc[5] += b.y; acc[6] += b.z; acc[7] += b.w;
        acc[8] += c.x; acc[9] += c.y; acc[10] += c.z;
    }
    {
        const float4* p = (const float4*)(Z1p + (size_t)v * PSTRIDE);
        float4 a = p[0], b = p[1], c = p[2];
        acc[0] += a.x; acc[1] += a.y; acc[2] += a.z; acc[3] += a.w;
        acc[4] += b.x; acc[5] += b.y; acc[6] += b.z; acc[7] += b.w;
        acc[8] += c.x; acc[9] += c.y; acc[10] += c.z;
    }
    float dd = dinv[v];
    float rv = r[v];
    float h[OUT_H];
    #pragma unroll
    for (int j = 0; j < OUT_H; ++j) {
        float t = dd * acc[j] + rv * sbb[j] + sb2[j];
        h[j] = t > 0.f ? t : 0.f;   // relu
    }
    float o[NCLASS];
    #pragma unroll
    for (int j = 0; j < NCLASS; ++j) o[j] = sbc[j];
    const float4* ea = (const float4*)(emb_a + (size_t)v * NCLASS);  // 160B row, 16B aligned
    #pragma unroll
    for (int k4 = 0; k4 < NCLASS / 4; ++k4) {
        float4 a = ea[k4];
        #pragma unroll
        for (int j = 0; j < NCLASS; ++j) {
            o[j] += a.x * sWc[(4 * k4 + 0) * NCLASS + j];
            o[j] += a.y * sWc[(4 * k4 + 1) * NCLASS + j];
            o[j] += a.z * sWc[(4 * k4 + 2) * NCLASS + j];
            o[j] += a.w * sWc[(4 * k4 + 3) * NCLASS + j];
        }
    }
    #pragma unroll
    for (int k = 0; k < OUT_H; ++k) {
        #pragma unroll
        for (int j = 0; j < NCLASS; ++j) o[j] += h[k] * sWc[(NCLASS + k) * NCLASS + j];
    }
    float4* orow = (float4*)(out + (size_t)v * NCLASS);
    #pragma unroll
    for (int j4 = 0; j4 < NCLASS / 4; ++j4) {
        orow[j4] = make_float4(o[4 * j4], o[4 * j4 + 1], o[4 * j4 + 2], o[4 * j4 + 3]);
    }
}

extern "C" void kernel_launch(void* const* d_in, const int* in_sizes, int n_in,
                              void* d_out, int out_size, void* d_ws, size_t ws_size,
                              hipStream_t stream) {
    const float* X     = (const float*)d_in[0];   // [100000, 18]
    const int*   ei    = (const int*)d_in[1];     // [2, 1600000]
    const float* emb_a = (const float*)d_in[2];   // [100000, 40]
    const float* W1    = (const float*)d_in[3];   // [18, 256]
    const float* b1    = (const float*)d_in[4];   // [256]
    const float* W2    = (const float*)d_in[5];   // [256, 11]
    const float* b2    = (const float*)d_in[6];   // [11]
    const float* Wc    = (const float*)d_in[7];   // [51, 40]
    const float* bc    = (const float*)d_in[8];   // [40]
    float* out = (float*)d_out;

    // workspace layout (256B-aligned chunks)
    char* ws = (char*)d_ws;
    size_t off = 0;
    auto alloc = [&](size_t nbytes) {
        void* p = (void*)(ws + off);
        off += ((nbytes + 255) / 256) * 256;
        return p;
    };
    int*   cnt    = (int*)  alloc(N_NODES * sizeof(int));
    int*   incl   = (int*)  alloc(N_NODES * sizeof(int));
    int*   bsum   = (int*)  alloc(NB_SCAN * sizeof(int));
    int*   boff   = (int*)  alloc(NB_SCAN * sizeof(int));
    int*   rowptr = (int*)  alloc((N_NODES + 1) * sizeof(int));
    int*   cursor = (int*)  alloc(N_NODES * sizeof(int));
    float* dinv   = (float*)alloc(N_NODES * sizeof(float));
    int*   col    = (int*)  alloc((size_t)N_EDGES * sizeof(int));
    float* W12    = (float*)alloc(IN_H * OUT_H * sizeof(float));
    float* bb     = (float*)alloc(OUT_H * sizeof(float));
    float* Pp     = (float*)alloc((size_t)N_NODES * PSTRIDE * sizeof(float));
    float* Z1p    = (float*)alloc((size_t)N_NODES * PSTRIDE * sizeof(float));
    float* rvec   = (float*)alloc(N_NODES * sizeof(float));

    const int B = 256;
    int gN = (N_NODES + B - 1) / B;     // 391
    int gE = (N_EDGES + B - 1) / B;     // 6250

    k_cnt_init<<<gN, B, 0, stream>>>(cnt, N_NODES);
    k_count   <<<gE, B, 0, stream>>>(ei + N_EDGES, cnt, N_EDGES);
    k_scanA   <<<NB_SCAN, SCAN_B, 0, stream>>>(cnt, incl, bsum, N_NODES);
    k_scanB   <<<1, 1, 0, stream>>>(bsum, boff, NB_SCAN);
    k_scanC   <<<gN, B, 0, stream>>>(cnt, incl, boff, rowptr, cursor, dinv, N_NODES);
    k_fill    <<<gE, B, 0, stream>>>(ei, cursor, col, N_EDGES);
    k_w12     <<<1, B, 0, stream>>>(W1, b1, W2, W12, bb);
    k_P       <<<gN, B, 0, stream>>>(X, W12, dinv, Pp, N_NODES);
    k_gather1 <<<gN, B, 0, stream>>>(rowptr, col, dinv, Pp, Z1p, rvec, N_NODES);
    k_final   <<<gN, B, 0, stream>>>(rowptr, col, dinv, Z1p, rvec, bb, b2, emb_a,
                                     Wc, bc, out, N_NODES);
}

// Round 3
// 156.722 us; speedup vs baseline: 16.0238x; 1.9783x over previous
//
#include <hip/hip_runtime.h>

#define N_NODES 100000
#define N_EDGES 1600000
#define IN_H 18
#define OUT_H 11
#define NCLASS 40
#define NHID 256
#define PSTRIDE 12            // 11 features padded to 12 floats (48B, float4-able)

// ---- bucket-sort geometry ----
#define BBITS 9
#define BINS 512                            // nodes per bucket (low 9 bits)
#define NB 196                              // ceil(100000/512) buckets (high bits)
#define NBLK 800                            // edge-chunk blocks
#define CHUNK 2000                          // NBLK*CHUNK == N_EDGES
#define SRC_MASK 0x1FFFF                    // 17-bit src payload

// ---------------- K1a: per-block bucket histogram (LDS atomics only) ----------------
__global__ void k_hist(const int* __restrict__ dst, int* __restrict__ bh, int E) {
    __shared__ int h[NB];
    int t = threadIdx.x;
    if (t < NB) h[t] = 0;
    __syncthreads();
    int base = blockIdx.x * CHUNK;
    int end = base + CHUNK; if (end > E) end = E;
    for (int i = base + t; i < end; i += blockDim.x)
        atomicAdd(&h[dst[i] >> BBITS], 1);
    __syncthreads();
    if (t < NB) bh[t * NBLK + blockIdx.x] = h[t];   // [bin][blk]
}

// ---------------- S1: bucket totals ----------------
__global__ void k_btot(const int* __restrict__ bh, int* __restrict__ btot) {
    __shared__ int s[256];
    int b = blockIdx.x, t = threadIdx.x;
    int sum = 0;
    for (int k = t; k < NBLK; k += 256) sum += bh[b * NBLK + k];
    s[t] = sum;
    __syncthreads();
    for (int off = 128; off > 0; off >>= 1) {
        if (t < off) s[t] += s[t + off];
        __syncthreads();
    }
    if (t == 0) btot[b] = s[0];
}

// ---------------- S2: exclusive scan of bucket totals ----------------
__global__ void k_bstart(const int* __restrict__ btot, int* __restrict__ bstart) {
    if (threadIdx.x == 0 && blockIdx.x == 0) {
        int run = 0;
        for (int b = 0; b < NB; ++b) { bstart[b] = run; run += btot[b]; }
        bstart[NB] = run;
    }
}

// ---------------- S3: per-(bin,blk) absolute offsets, in place ----------------
__global__ __launch_bounds__(1024) void k_boff(int* __restrict__ bh,
                                               const int* __restrict__ bstart) {
    __shared__ int s0[1024], s1[1024];
    int b = blockIdx.x, t = threadIdx.x;
    int v = (t < NBLK) ? bh[b * NBLK + t] : 0;
    s0[t] = v;
    __syncthreads();
    int* c = s0; int* n = s1;
    for (int off = 1; off < 1024; off <<= 1) {
        n[t] = c[t] + ((t >= off) ? c[t - off] : 0);
        __syncthreads();
        int* tmp = c; c = n; n = tmp;
    }
    if (t < NBLK) bh[b * NBLK + t] = c[t] - v + bstart[b];   // exclusive + bucket base
}

// ---------------- K1c: scatter edges into buckets (LDS cursors) ----------------
__global__ void k_bucket(const int* __restrict__ ei, const int* __restrict__ bh,
                         unsigned int* __restrict__ packed, int E) {
    __shared__ int cur[NB];
    int t = threadIdx.x;
    if (t < NB) cur[t] = bh[t * NBLK + blockIdx.x];
    __syncthreads();
    int base = blockIdx.x * CHUNK;
    int end = base + CHUNK; if (end > E) end = E;
    for (int i = base + t; i < end; i += blockDim.x) {
        int s = ei[i];
        int d = ei[E + i];
        int slot = atomicAdd(&cur[d >> BBITS], 1);
        packed[slot] = ((unsigned)(d & (BINS - 1)) << 17) | (unsigned)s;
    }
}

// ---------------- K2: per-bucket counting sort -> col, rowptr, dinv ----------------
__global__ __launch_bounds__(1024)
void k_sort(const unsigned int* __restrict__ packed, const int* __restrict__ bstart,
            int* __restrict__ col, int* __restrict__ rowptr, float* __restrict__ dinv) {
    __shared__ int hist[BINS];
    __shared__ int s0[BINS], s1[BINS];
    __shared__ int cur[BINS];
    int b = blockIdx.x, t = threadIdx.x;
    int beg = bstart[b], end = bstart[b + 1];
    if (t < BINS) hist[t] = 0;
    __syncthreads();
    for (int i = beg + t; i < end; i += blockDim.x)
        atomicAdd(&hist[packed[i] >> 17], 1);
    __syncthreads();
    if (t < BINS) s0[t] = hist[t];
    __syncthreads();
    int* c = s0; int* n = s1;
    for (int off = 1; off < BINS; off <<= 1) {
        if (t < BINS) n[t] = c[t] + ((t >= off) ? c[t - off] : 0);
        __syncthreads();
        int* tmp = c; c = n; n = tmp;
    }
    if (t < BINS) {
        int excl = c[t] - hist[t];
        int gbase = beg + excl;
        cur[t] = gbase;
        int node = (b << BBITS) + t;
        if (node <= N_NODES) rowptr[node] = gbase;     // node==N_NODES lands on E
        if (node < N_NODES)  dinv[node] = rsqrtf((float)(hist[t] + 1));
    }
    __syncthreads();
    for (int i = beg + t; i < end; i += blockDim.x) {
        unsigned p = packed[i];
        int slot = atomicAdd(&cur[p >> 17], 1);
        col[slot] = (int)(p & SRC_MASK);
    }
}

// ---------------- W12 = W1 @ W2, bb = b1 @ W2 (one block) ----------------
__global__ void k_w12(const float* __restrict__ W1, const float* __restrict__ b1,
                      const float* __restrict__ W2,
                      float* __restrict__ W12, float* __restrict__ bb) {
    int t = threadIdx.x;
    if (t < IN_H * OUT_H) {
        int i = t / OUT_H, j = t % OUT_H;
        float s = 0.f;
        for (int k = 0; k < NHID; ++k) s += W1[i * NHID + k] * W2[k * OUT_H + j];
        W12[t] = s;
    } else if (t < IN_H * OUT_H + OUT_H) {
        int j = t - IN_H * OUT_H;
        float s = 0.f;
        for (int k = 0; k < NHID; ++k) s += b1[k] * W2[k * OUT_H + j];
        bb[j] = s;
    }
}

// ---------------- P' = dinv * (X @ W12), padded rows ----------------
__global__ void k_P(const float* __restrict__ X, const float* __restrict__ W12g,
                    const float* __restrict__ dinv, float* __restrict__ Pp, int n) {
    __shared__ float sW[IN_H * OUT_H];
    int t = threadIdx.x;
    if (t < IN_H * OUT_H) sW[t] = W12g[t];
    __syncthreads();
    int v = blockIdx.x * blockDim.x + t;
    if (v >= n) return;
    float x[IN_H];
    const float2* xr = (const float2*)(X + (size_t)v * IN_H);
    #pragma unroll
    for (int k = 0; k < IN_H / 2; ++k) {
        float2 c = xr[k];
        x[2 * k] = c.x; x[2 * k + 1] = c.y;
    }
    float dv = dinv[v];
    float* pr = Pp + (size_t)v * PSTRIDE;
    #pragma unroll
    for (int j = 0; j < OUT_H; ++j) {
        float s = 0.f;
        #pragma unroll
        for (int k = 0; k < IN_H; ++k) s += x[k] * sW[k * OUT_H + j];
        pr[j] = dv * s;
    }
    pr[OUT_H] = 0.f;
}

// ---------------- gather pass 1: Z1' = dinv^2*(sum P'[src] + P'[v]), r ----------------
__global__ void k_gather1(const int* __restrict__ rowptr, const int* __restrict__ col,
                          const float* __restrict__ dinv, const float* __restrict__ Pp,
                          float* __restrict__ Z1p, float* __restrict__ r, int n) {
    int v = blockIdx.x * blockDim.x + threadIdx.x;
    if (v >= n) return;
    int beg = rowptr[v], end = rowptr[v + 1];
    float acc[11];
    #pragma unroll
    for (int j = 0; j < 11; ++j) acc[j] = 0.f;
    float rs = 0.f;
    for (int e = beg; e < end; ++e) {
        int s = col[e];
        rs += dinv[s];
        const float4* p = (const float4*)(Pp + (size_t)s * PSTRIDE);
        float4 a = p[0], b = p[1], c = p[2];
        acc[0] += a.x; acc[1] += a.y; acc[2] += a.z; acc[3] += a.w;
        acc[4] += b.x; acc[5] += b.y; acc[6] += b.z; acc[7] += b.w;
        acc[8] += c.x; acc[9] += c.y; acc[10] += c.z;
    }
    {
        const float4* p = (const float4*)(Pp + (size_t)v * PSTRIDE);
        float4 a = p[0], b = p[1], c = p[2];
        acc[0] += a.x; acc[1] += a.y; acc[2] += a.z; acc[3] += a.w;
        acc[4] += b.x; acc[5] += b.y; acc[6] += b.z; acc[7] += b.w;
        acc[8] += c.x; acc[9] += c.y; acc[10] += c.z;
    }
    float dd = dinv[v];
    float s2 = dd * dd;
    float* z = Z1p + (size_t)v * PSTRIDE;
    #pragma unroll
    for (int j = 0; j < 11; ++j) z[j] = s2 * acc[j];
    z[OUT_H] = 0.f;
    r[v] = dd * (rs + dd);
}

// ---------------- gather pass 2 fused with final matmul ----------------
__global__ void k_final(const int* __restrict__ rowptr, const int* __restrict__ col,
                        const float* __restrict__ dinv, const float* __restrict__ Z1p,
                        const float* __restrict__ r, const float* __restrict__ bbg,
                        const float* __restrict__ b2g, const float* __restrict__ emb_a,
                        const float* __restrict__ Wc, const float* __restrict__ bc,
                        float* __restrict__ out, int n) {
    __shared__ float sWc[(NCLASS + OUT_H) * NCLASS];   // 51*40
    __shared__ float sbc[NCLASS];
    __shared__ float sb2[OUT_H];
    __shared__ float sbb[OUT_H];
    for (int t = threadIdx.x; t < (NCLASS + OUT_H) * NCLASS; t += blockDim.x) sWc[t] = Wc[t];
    if (threadIdx.x < NCLASS) sbc[threadIdx.x] = bc[threadIdx.x];
    if (threadIdx.x < OUT_H) { sb2[threadIdx.x] = b2g[threadIdx.x]; sbb[threadIdx.x] = bbg[threadIdx.x]; }
    __syncthreads();
    int v = blockIdx.x * blockDim.x + threadIdx.x;
    if (v >= n) return;
    int beg = rowptr[v], end = rowptr[v + 1];
    float acc[11];
    #pragma unroll
    for (int j = 0; j < 11; ++j) acc[j] = 0.f;
    for (int e = beg; e < end; ++e) {
        int s = col[e];
        const float4* p = (const float4*)(Z1p + (size_t)s * PSTRIDE);
        float4 a = p[0], b = p[1], c = p[2];
        acc[0] += a.x; acc[1] += a.y; acc[2] += a.z; acc[3] += a.w;
        acc[4] += b.x; acc[5] += b.y; acc[6] += b.z; acc[7] += b.w;
        acc[8] += c.x; acc[9] += c.y; acc[10] += c.z;
    }
    {
        const float4* p = (const float4*)(Z1p + (size_t)v * PSTRIDE);
        float4 a = p[0], b = p[1], c = p[2];
        acc[0] += a.x; acc[1] += a.y; acc[2] += a.z; acc[3] += a.w;
        acc[4] += b.x; acc[5] += b.y; acc[6] += b.z; acc[7] += b.w;
        acc[8] += c.x; acc[9] += c.y; acc[10] += c.z;
    }
    float dd = dinv[v];
    float rv = r[v];
    float h[OUT_H];
    #pragma unroll
    for (int j = 0; j < OUT_H; ++j) {
        float tv = dd * acc[j] + rv * sbb[j] + sb2[j];
        h[j] = tv > 0.f ? tv : 0.f;   // relu
    }
    float o[NCLASS];
    #pragma unroll
    for (int j = 0; j < NCLASS; ++j) o[j] = sbc[j];
    const float4* ea = (const float4*)(emb_a + (size_t)v * NCLASS);
    #pragma unroll
    for (int k4 = 0; k4 < NCLASS / 4; ++k4) {
        float4 a = ea[k4];
        #pragma unroll
        for (int j = 0; j < NCLASS; ++j) {
            o[j] += a.x * sWc[(4 * k4 + 0) * NCLASS + j];
            o[j] += a.y * sWc[(4 * k4 + 1) * NCLASS + j];
            o[j] += a.z * sWc[(4 * k4 + 2) * NCLASS + j];
            o[j] += a.w * sWc[(4 * k4 + 3) * NCLASS + j];
        }
    }
    #pragma unroll
    for (int k = 0; k < OUT_H; ++k) {
        #pragma unroll
        for (int j = 0; j < NCLASS; ++j) o[j] += h[k] * sWc[(NCLASS + k) * NCLASS + j];
    }
    float4* orow = (float4*)(out + (size_t)v * NCLASS);
    #pragma unroll
    for (int j4 = 0; j4 < NCLASS / 4; ++j4)
        orow[j4] = make_float4(o[4 * j4], o[4 * j4 + 1], o[4 * j4 + 2], o[4 * j4 + 3]);
}

extern "C" void kernel_launch(void* const* d_in, const int* in_sizes, int n_in,
                              void* d_out, int out_size, void* d_ws, size_t ws_size,
                              hipStream_t stream) {
    const float* X     = (const float*)d_in[0];
    const int*   ei    = (const int*)d_in[1];
    const float* emb_a = (const float*)d_in[2];
    const float* W1    = (const float*)d_in[3];
    const float* b1    = (const float*)d_in[4];
    const float* W2    = (const float*)d_in[5];
    const float* b2    = (const float*)d_in[6];
    const float* Wc    = (const float*)d_in[7];
    const float* bc    = (const float*)d_in[8];
    float* out = (float*)d_out;

    char* ws = (char*)d_ws;
    size_t off = 0;
    auto alloc = [&](size_t nbytes) {
        void* p = (void*)(ws + off);
        off += ((nbytes + 255) / 256) * 256;
        return p;
    };
    // region bh is dead after k_bucket -> rvec aliases it.
    // region packed is dead after k_sort -> Pp aliases it.
    char* bh_base = (char*)alloc((size_t)NB * NBLK * sizeof(int));   // 627 KB
    int*   bh     = (int*)bh_base;
    float* rvec   = (float*)bh_base;                                 // alias (>=400KB fits)
    int*   btot   = (int*)  alloc(NB * sizeof(int));
    int*   bstart = (int*)  alloc((NB + 1) * sizeof(int));
    char* pk_base = (char*)alloc((size_t)N_EDGES * sizeof(unsigned int));  // 6.4 MB
    unsigned int* packed = (unsigned int*)pk_base;
    float* Pp     = (float*)pk_base;                                 // alias (4.8MB fits)
    int*   col    = (int*)  alloc((size_t)N_EDGES * sizeof(int));
    int*   rowptr = (int*)  alloc((N_NODES + 1) * sizeof(int));
    float* dinv   = (float*)alloc(N_NODES * sizeof(float));
    float* W12    = (float*)alloc(IN_H * OUT_H * sizeof(float));
    float* bb     = (float*)alloc(OUT_H * sizeof(float));
    float* Z1p    = (float*)alloc((size_t)N_NODES * PSTRIDE * sizeof(float));

    const int B = 256;
    int gN = (N_NODES + B - 1) / B;

    k_hist   <<<NBLK, B, 0, stream>>>(ei + N_EDGES, bh, N_EDGES);
    k_btot   <<<NB, 256, 0, stream>>>(bh, btot);
    k_bstart <<<1, 64, 0, stream>>>(btot, bstart);
    k_boff   <<<NB, 1024, 0, stream>>>(bh, bstart);
    k_bucket <<<NBLK, B, 0, stream>>>(ei, bh, packed, N_EDGES);
    k_sort   <<<NB, 1024, 0, stream>>>(packed, bstart, col, rowptr, dinv);
    k_w12    <<<1, B, 0, stream>>>(W1, b1, W2, W12, bb);
    k_P      <<<gN, B, 0, stream>>>(X, W12, dinv, Pp, N_NODES);
    k_gather1<<<gN, B, 0, stream>>>(rowptr, col, dinv, Pp, Z1p, rvec, N_NODES);
    k_final  <<<gN, B, 0, stream>>>(rowptr, col, dinv, Z1p, rvec, bb, b2, emb_a,
                                    Wc, bc, out, N_NODES);
}